// Round 4
// baseline (12360.535 us; speedup 1.0000x reference)
//
#include <hip/hip_runtime.h>
#include <hip/hip_bf16.h>

// Problem constants
constexpr int L = 4, D = 512, H = 8, DFF = 2048, NSEQ = 512, B = 16, C = 3;
constexpr int DH = D / H;          // 64
constexpr int M = B * NSEQ;        // 8192 tokens
constexpr int BND = B * NSEQ * D;  // 4,194,304

__device__ __forceinline__ float block_reduce_sum(float v, float* red) {
    int tid = threadIdx.x;
    red[tid] = v; __syncthreads();
#pragma unroll
    for (int s = 128; s > 0; s >>= 1) {
        if (tid < s) red[tid] += red[tid + s];
        __syncthreads();
    }
    float r = red[0];
    __syncthreads();
    return r;
}
__device__ __forceinline__ float block_reduce_max(float v, float* red) {
    int tid = threadIdx.x;
    red[tid] = v; __syncthreads();
#pragma unroll
    for (int s = 128; s > 0; s >>= 1) {
        if (tid < s) red[tid] = fmaxf(red[tid], red[tid + s]);
        __syncthreads();
    }
    float r = red[0];
    __syncthreads();
    return r;
}

// ---------------------------------------------------------------------------
// 1. Embedding * sqrt(D) + sinusoidal PE.  x[b,n,d], one thread per element.
__global__ __launch_bounds__(256) void embed_pe_kernel(
    const int* __restrict__ src, const float* __restrict__ emb,
    float* __restrict__ x)
{
    int idx = blockIdx.x * 256 + threadIdx.x;   // over B*N*D
    int d = idx & (D - 1);
    int t = idx >> 9;            // b*N + n
    int n = t & (NSEQ - 1);
    int b = t >> 9;
    int tok = src[n * B + b];
    float e = emb[(size_t)tok * D + d] * 22.627416997969522f;  // sqrt(512)
    float div = expf((float)(d & ~1) * -0.01798894603797866f); // -ln(1e4)/512
    float ang = (float)n * div;
    float pe = (d & 1) ? cosf(ang) : sinf(ang);
    x[idx] = e + pe;
}

// ---------------------------------------------------------------------------
// 2. LayerNorm over D=512, one block (256 thr) per row.
__global__ __launch_bounds__(256) void ln_kernel(
    const float* __restrict__ in, const float* __restrict__ g,
    const float* __restrict__ bt, float* __restrict__ out)
{
    __shared__ float red[256];
    int row = blockIdx.x, tid = threadIdx.x;
    const float* p = in + (size_t)row * D;
    float v0 = p[tid], v1 = p[tid + 256];
    float mean = block_reduce_sum(v0 + v1, red) * (1.0f / D);
    float d0 = v0 - mean, d1 = v1 - mean;
    float var = block_reduce_sum(d0 * d0 + d1 * d1, red) * (1.0f / D);
    float rstd = rsqrtf(var + 1e-6f);
    out[(size_t)row * D + tid]       = d0 * rstd * g[tid]       + bt[tid];
    out[(size_t)row * D + tid + 256] = d1 * rstd * g[tid + 256] + bt[tid + 256];
}

// ---------------------------------------------------------------------------
// 3. Tiled GEMM: out[M,Ndim] = A[M,Kdim] @ W[Kdim,Ndim] + bias. All fp32.
//    64x64 tile, BK=16, 256 threads, 4x4 micro-tile per thread.
template<bool ADD, bool RELU>
__global__ __launch_bounds__(256) void gemm_kernel(
    const float* __restrict__ A, const float* __restrict__ W,
    const float* __restrict__ bias, float* __restrict__ out,
    int Kdim, int Ndim)
{
    constexpr int BM = 64, BN = 64, BK = 16;
    __shared__ float As[BM][BK + 4];   // 64 x 20
    __shared__ float Bs[BK][BN + 4];   // 16 x 68

    int tid = threadIdx.x;
    int tx = tid & 15;          // 0..15 col group
    int ty = tid >> 4;          // 0..15 row group
    int n0 = blockIdx.x * BN;
    int m0 = blockIdx.y * BM;

    int ar  = tid >> 2;          // 0..63  A row
    int akg = (tid & 3) << 2;    // 0,4,8,12 A col group
    int br  = tid >> 4;          // 0..15  W row
    int bcg = (tid & 15) << 2;   // W col group

    float acc[4][4] = {};

    for (int kb = 0; kb < Kdim; kb += BK) {
        float4 av = *reinterpret_cast<const float4*>(A + (size_t)(m0 + ar) * Kdim + kb + akg);
        *reinterpret_cast<float4*>(&As[ar][akg]) = av;
        float4 bv = *reinterpret_cast<const float4*>(W + (size_t)(kb + br) * Ndim + n0 + bcg);
        *reinterpret_cast<float4*>(&Bs[br][bcg]) = bv;
        __syncthreads();
#pragma unroll
        for (int kk = 0; kk < BK; kk++) {
            float a0 = As[ty * 4 + 0][kk];
            float a1 = As[ty * 4 + 1][kk];
            float a2 = As[ty * 4 + 2][kk];
            float a3 = As[ty * 4 + 3][kk];
            float4 b = *reinterpret_cast<const float4*>(&Bs[kk][tx * 4]);
            acc[0][0] += a0 * b.x; acc[0][1] += a0 * b.y; acc[0][2] += a0 * b.z; acc[0][3] += a0 * b.w;
            acc[1][0] += a1 * b.x; acc[1][1] += a1 * b.y; acc[1][2] += a1 * b.z; acc[1][3] += a1 * b.w;
            acc[2][0] += a2 * b.x; acc[2][1] += a2 * b.y; acc[2][2] += a2 * b.z; acc[2][3] += a2 * b.w;
            acc[3][0] += a3 * b.x; acc[3][1] += a3 * b.y; acc[3][2] += a3 * b.z; acc[3][3] += a3 * b.w;
        }
        __syncthreads();
    }

    float bb[4];
#pragma unroll
    for (int j = 0; j < 4; j++) bb[j] = bias[n0 + tx * 4 + j];
#pragma unroll
    for (int i = 0; i < 4; i++) {
        int m = m0 + ty * 4 + i;
        float* op = out + (size_t)m * Ndim + n0 + tx * 4;
#pragma unroll
        for (int j = 0; j < 4; j++) {
            float v = acc[i][j] + bb[j];
            if (RELU) v = fmaxf(v, 0.0f);
            if (ADD) op[j] += v; else op[j] = v;
        }
    }
}

// ---------------------------------------------------------------------------
// 4. Attention: one block per (b, h, query i). Scores row in LDS, softmax,
//    weighted V sum. q/k/v are [B,N,D] fp32 with head slice at h*DH.
__global__ __launch_bounds__(256) void attn_kernel(
    const float* __restrict__ q, const float* __restrict__ k,
    const float* __restrict__ v, const int* __restrict__ lengths,
    float* __restrict__ ctx)
{
    __shared__ float sc[NSEQ];
    __shared__ float qv[DH];
    __shared__ float red[256];

    int tid = threadIdx.x;
    int i  = blockIdx.x & (NSEQ - 1);
    int bh = blockIdx.x >> 9;
    int hh = bh & (H - 1);
    int b  = bh >> 3;

    const float* qp = q + ((size_t)(b * NSEQ + i) * D + hh * DH);
    if (tid < DH) qv[tid] = qp[tid];
    __syncthreads();

    int len = lengths[b];
    for (int j = tid; j < NSEQ; j += 256) {
        const float* kp = k + ((size_t)(b * NSEQ + j) * D + hh * DH);
        float s = 0.0f;
#pragma unroll
        for (int d = 0; d < DH; d++) s += qv[d] * kp[d];
        sc[j] = (j < len) ? s * 0.125f : -1e9f;
    }
    __syncthreads();

    float lm = fmaxf(sc[tid], sc[tid + 256]);
    float mx = block_reduce_max(lm, red);

    float ls = 0.0f;
    for (int j = tid; j < NSEQ; j += 256) {
        float e = __expf(sc[j] - mx);
        sc[j] = e;
        ls += e;
    }
    float tot = block_reduce_sum(ls, red);   // barrier also orders sc[] writes
    float inv = 1.0f / tot;

    int d = tid & 63;
    int p = tid >> 6;
    const float* vp = v + ((size_t)b * NSEQ * D + hh * DH + d);
    float a = 0.0f;
    for (int j = p; j < NSEQ; j += 4) a += sc[j] * vp[(size_t)j * D];
    red[tid] = a;
    __syncthreads();
    if (tid < DH) {
        float r = (red[tid] + red[tid + 64] + red[tid + 128] + red[tid + 192]) * inv;
        ctx[((size_t)(b * NSEQ + i)) * D + hh * DH + tid] = r;
    }
}

// ---------------------------------------------------------------------------
// 5. Final LN output -> attn_res (float32, [N,B,D] layout)
__global__ __launch_bounds__(256) void store_attnres(
    const float* __restrict__ hf, float* __restrict__ out)
{
    int idx = blockIdx.x * 256 + threadIdx.x;  // over N*B*D (output linear)
    int d  = idx & (D - 1);
    int nb = idx >> 9;      // n*B + b
    int b  = nb & (B - 1);
    int n  = nb >> 4;
    out[idx] = hf[((size_t)(b * NSEQ + n)) * D + d];
}

// ---------------------------------------------------------------------------
// 6. la = hf @ inf_W[:D], lb = hf @ inf_W[D:].  One block per token.
__global__ __launch_bounds__(256) void lalb_kernel(
    const float* __restrict__ hf, const float* __restrict__ infW,
    float* __restrict__ la, float* __restrict__ lb)
{
    __shared__ float red[256];
    int t = blockIdx.x, tid = threadIdx.x;
    const float* p = hf + (size_t)t * D;
    float x0 = p[tid], x1 = p[tid + 256];
#pragma unroll
    for (int c = 0; c < C; c++) {
        float pa = x0 * infW[(size_t)tid * C + c] + x1 * infW[(size_t)(tid + 256) * C + c];
        float sa = block_reduce_sum(pa, red);
        if (tid == 0) la[t * C + c] = sa;
        float pb = x0 * infW[(size_t)(tid + 512) * C + c] + x1 * infW[(size_t)(tid + 768) * C + c];
        float sb = block_reduce_sum(pb, red);
        if (tid == 0) lb[t * C + c] = sb;
    }
}

// ---------------------------------------------------------------------------
// 7. logits[b,i,j,:] = la[b,i,:] + lb[b,j,:]; log_softmax over C=3;
//    store float32 at [(i*N+j)*B + b]*C + c.
__global__ __launch_bounds__(256) void logits_kernel(
    const float* __restrict__ la, const float* __restrict__ lb,
    float* __restrict__ out)
{
    int idx = blockIdx.x * 256 + threadIdx.x;  // over N*N*B
    int b  = idx & (B - 1);
    int ij = idx >> 4;
    int j  = ij & (NSEQ - 1);
    int i  = ij >> 9;
    const float* pa = la + ((size_t)(b * NSEQ + i)) * C;
    const float* pb = lb + ((size_t)(b * NSEQ + j)) * C;
    float l0 = pa[0] + pb[0];
    float l1 = pa[1] + pb[1];
    float l2 = pa[2] + pb[2];
    float m = fmaxf(l0, fmaxf(l1, l2));
    float lse = m + logf(__expf(l0 - m) + __expf(l1 - m) + __expf(l2 - m));
    out[(size_t)idx * 3 + 0] = l0 - lse;
    out[(size_t)idx * 3 + 1] = l1 - lse;
    out[(size_t)idx * 3 + 2] = l2 - lse;
}

// ---------------------------------------------------------------------------
extern "C" void kernel_launch(void* const* d_in, const int* in_sizes, int n_in,
                              void* d_out, int out_size, void* d_ws, size_t ws_size,
                              hipStream_t stream)
{
    const int*   src     = (const int*)  d_in[0];
    const int*   lengths = (const int*)  d_in[1];
    const float* emb     = (const float*)d_in[2];
    const float* ln1_g   = (const float*)d_in[3];
    const float* ln1_b   = (const float*)d_in[4];
    const float* Wq      = (const float*)d_in[5];
    const float* bq      = (const float*)d_in[6];
    const float* Wk      = (const float*)d_in[7];
    const float* bk      = (const float*)d_in[8];
    const float* Wv      = (const float*)d_in[9];
    const float* bv      = (const float*)d_in[10];
    const float* Wo      = (const float*)d_in[11];
    const float* bo      = (const float*)d_in[12];
    const float* ln2_g   = (const float*)d_in[13];
    const float* ln2_b   = (const float*)d_in[14];
    const float* W1      = (const float*)d_in[15];
    const float* b1      = (const float*)d_in[16];
    const float* W2      = (const float*)d_in[17];
    const float* b2      = (const float*)d_in[18];
    const float* lnf_g   = (const float*)d_in[19];
    const float* lnf_b   = (const float*)d_in[20];
    const float* infW    = (const float*)d_in[21];

    // Workspace layout (fp32), 5*BND floats = exactly 80 MiB:
    //   x   [B,N,D]      4,194,304    [0, 16 MiB)
    //   h   [B,N,D]      4,194,304    [16, 32 MiB)
    //   big 3*BND       12,582,912    [32, 80 MiB)  (q,k,v; FFN hidden halves;
    //                                  la/lb reuse after layers are done)
    float* ws  = (float*)d_ws;
    float* x   = ws;
    float* h   = x + BND;
    float* big = h + BND;
    float* qb  = big;
    float* kb  = big + BND;
    float* vb  = big + 2 * BND;
    float* la  = big;                       // big is free after the L layers
    float* lb  = la + (size_t)M * C;

    dim3 blk(256);
    dim3 g_dd(D / 64, M / 64);        // 8 x 128
    dim3 g_dffh(DFF / 64, M / 128);   // 32 x 64 (half the tokens)
    dim3 g_ddh(D / 64, M / 128);      // 8 x 64

    embed_pe_kernel<<<BND / 256, blk, 0, stream>>>(src, emb, x);

    for (int l = 0; l < L; l++) {
        size_t wdd = (size_t)l * D * D, bd = (size_t)l * D;
        size_t wdf = (size_t)l * D * DFF, bf = (size_t)l * DFF;
        ln_kernel<<<M, blk, 0, stream>>>(x, ln1_g + bd, ln1_b + bd, h);
        gemm_kernel<false, false><<<g_dd, blk, 0, stream>>>(h, Wq + wdd, bq + bd, qb, D, D);
        gemm_kernel<false, false><<<g_dd, blk, 0, stream>>>(h, Wk + wdd, bk + bd, kb, D, D);
        gemm_kernel<false, false><<<g_dd, blk, 0, stream>>>(h, Wv + wdd, bv + bd, vb, D, D);
        attn_kernel<<<B * H * NSEQ, blk, 0, stream>>>(qb, kb, vb, lengths, h);
        gemm_kernel<true, false><<<g_dd, blk, 0, stream>>>(h, Wo + wdd, bo + bd, x, D, D);
        ln_kernel<<<M, blk, 0, stream>>>(x, ln2_g + bd, ln2_b + bd, h);
        // FFN in two half-M passes so the hidden fits in big (8.4M <= 12.6M floats)
        for (int hf = 0; hf < 2; hf++) {
            const float* hp = h + (size_t)hf * (M / 2) * D;
            float*       xp = x + (size_t)hf * (M / 2) * D;
            gemm_kernel<false, true><<<g_dffh, blk, 0, stream>>>(hp, W1 + wdf, b1 + bf, big, D, DFF);
            gemm_kernel<true, false><<<g_ddh, blk, 0, stream>>>(big, W2 + wdf, b2 + bd, xp, DFF, D);
        }
    }

    ln_kernel<<<M, blk, 0, stream>>>(x, lnf_g, lnf_b, h);
    store_attnres<<<(NSEQ * B * D) / 256, blk, 0, stream>>>(h, (float*)d_out);
    lalb_kernel<<<M, blk, 0, stream>>>(h, infW, la, lb);
    logits_kernel<<<(NSEQ * NSEQ * B) / 256, blk, 0, stream>>>(la, lb, (float*)d_out + (size_t)NSEQ * B * D);
}

// Round 5
// 5198.288 us; speedup vs baseline: 2.3778x; 2.3778x over previous
//
#include <hip/hip_runtime.h>
#include <hip/hip_bf16.h>

// Problem constants
constexpr int L = 4, D = 512, H = 8, DFF = 2048, NSEQ = 512, B = 16, C = 3;
constexpr int DH = D / H;          // 64
constexpr int M = B * NSEQ;        // 8192 tokens
constexpr int BND = B * NSEQ * D;  // 4,194,304

__device__ __forceinline__ float block_reduce_sum(float v, float* red) {
    int tid = threadIdx.x;
    red[tid] = v; __syncthreads();
#pragma unroll
    for (int s = 128; s > 0; s >>= 1) {
        if (tid < s) red[tid] += red[tid + s];
        __syncthreads();
    }
    float r = red[0];
    __syncthreads();
    return r;
}

// ---------------------------------------------------------------------------
// 1. Embedding * sqrt(D) + sinusoidal PE.  x[b,n,d], one thread per element.
__global__ __launch_bounds__(256) void embed_pe_kernel(
    const int* __restrict__ src, const float* __restrict__ emb,
    float* __restrict__ x)
{
    int idx = blockIdx.x * 256 + threadIdx.x;   // over B*N*D
    int d = idx & (D - 1);
    int t = idx >> 9;            // b*N + n
    int n = t & (NSEQ - 1);
    int b = t >> 9;
    int tok = src[n * B + b];
    float e = emb[(size_t)tok * D + d] * 22.627416997969522f;  // sqrt(512)
    float div = expf((float)(d & ~1) * -0.01798894603797866f); // -ln(1e4)/512
    float ang = (float)n * div;
    float pe = (d & 1) ? cosf(ang) : sinf(ang);
    x[idx] = e + pe;
}

// ---------------------------------------------------------------------------
// 2. LayerNorm over D=512, one block (256 thr) per row.
__global__ __launch_bounds__(256) void ln_kernel(
    const float* __restrict__ in, const float* __restrict__ g,
    const float* __restrict__ bt, float* __restrict__ out)
{
    __shared__ float red[256];
    int row = blockIdx.x, tid = threadIdx.x;
    const float* p = in + (size_t)row * D;
    float v0 = p[tid], v1 = p[tid + 256];
    float mean = block_reduce_sum(v0 + v1, red) * (1.0f / D);
    float d0 = v0 - mean, d1 = v1 - mean;
    float var = block_reduce_sum(d0 * d0 + d1 * d1, red) * (1.0f / D);
    float rstd = rsqrtf(var + 1e-6f);
    out[(size_t)row * D + tid]       = d0 * rstd * g[tid]       + bt[tid];
    out[(size_t)row * D + tid + 256] = d1 * rstd * g[tid + 256] + bt[tid + 256];
}

// ---------------------------------------------------------------------------
// 3. Tiled GEMM: out[M,Ndim] = A[M,Kdim] @ W[Kdim,Ndim] + bias. All fp32.
//    64x64 tile, BK=16, 256 threads, 4x4 micro-tile per thread.
template<bool ADD, bool RELU>
__global__ __launch_bounds__(256) void gemm_kernel(
    const float* __restrict__ A, const float* __restrict__ W,
    const float* __restrict__ bias, float* __restrict__ out,
    int Kdim, int Ndim)
{
    constexpr int BM = 64, BN = 64, BK = 16;
    __shared__ float As[BM][BK + 4];   // 64 x 20
    __shared__ float Bs[BK][BN + 4];   // 16 x 68

    int tid = threadIdx.x;
    int tx = tid & 15;          // 0..15 col group
    int ty = tid >> 4;          // 0..15 row group
    int n0 = blockIdx.x * BN;
    int m0 = blockIdx.y * BM;

    int ar  = tid >> 2;          // 0..63  A row
    int akg = (tid & 3) << 2;    // 0,4,8,12 A col group
    int br  = tid >> 4;          // 0..15  W row
    int bcg = (tid & 15) << 2;   // W col group

    float acc[4][4] = {};

    for (int kb = 0; kb < Kdim; kb += BK) {
        float4 av = *reinterpret_cast<const float4*>(A + (size_t)(m0 + ar) * Kdim + kb + akg);
        *reinterpret_cast<float4*>(&As[ar][akg]) = av;
        float4 bv = *reinterpret_cast<const float4*>(W + (size_t)(kb + br) * Ndim + n0 + bcg);
        *reinterpret_cast<float4*>(&Bs[br][bcg]) = bv;
        __syncthreads();
#pragma unroll
        for (int kk = 0; kk < BK; kk++) {
            float a0 = As[ty * 4 + 0][kk];
            float a1 = As[ty * 4 + 1][kk];
            float a2 = As[ty * 4 + 2][kk];
            float a3 = As[ty * 4 + 3][kk];
            float4 b = *reinterpret_cast<const float4*>(&Bs[kk][tx * 4]);
            acc[0][0] += a0 * b.x; acc[0][1] += a0 * b.y; acc[0][2] += a0 * b.z; acc[0][3] += a0 * b.w;
            acc[1][0] += a1 * b.x; acc[1][1] += a1 * b.y; acc[1][2] += a1 * b.z; acc[1][3] += a1 * b.w;
            acc[2][0] += a2 * b.x; acc[2][1] += a2 * b.y; acc[2][2] += a2 * b.z; acc[2][3] += a2 * b.w;
            acc[3][0] += a3 * b.x; acc[3][1] += a3 * b.y; acc[3][2] += a3 * b.z; acc[3][3] += a3 * b.w;
        }
        __syncthreads();
    }

    float bb[4];
#pragma unroll
    for (int j = 0; j < 4; j++) bb[j] = bias[n0 + tx * 4 + j];
#pragma unroll
    for (int i = 0; i < 4; i++) {
        int m = m0 + ty * 4 + i;
        float* op = out + (size_t)m * Ndim + n0 + tx * 4;
#pragma unroll
        for (int j = 0; j < 4; j++) {
            float v = acc[i][j] + bb[j];
            if (RELU) v = fmaxf(v, 0.0f);
            if (ADD) op[j] += v; else op[j] = v;
        }
    }
}

// ---------------------------------------------------------------------------
// 4. Flash-style attention: one block per (b, h, 64-query tile).
//    K/V staged in LDS 64x64 tiles; S = Q.K^T as LDS-fed 4x4 microtile GEMM;
//    online softmax (m/l/alpha in LDS); O accumulated in registers.
__global__ __launch_bounds__(256) void attn_tile_kernel(
    const float* __restrict__ qg, const float* __restrict__ kg,
    const float* __restrict__ vg, const int* __restrict__ lengths,
    float* __restrict__ ctx)
{
    __shared__ float Qs[64][68];    // padded: scalar column reads
    __shared__ float U[64][68];     // K^T during S-phase, then P (=exp scores)
    __shared__ float Vs[64][64];    // straight, float4 row reads are 2-way (free)
    __shared__ float mrow[64], lrow[64], arow[64];
    __shared__ float red[256];

    int tid = threadIdx.x;
    int qt = blockIdx.x, hh = blockIdx.y, b = blockIdx.z;
    int tr = tid >> 4, tc = tid & 15;        // 16x16 threads, 4x4 each
    int row = tid >> 2, seg = tid & 3;       // stats mapping: 4 thr/row

    const float* qbase = qg + ((size_t)(b * NSEQ + qt * 64)) * D + hh * DH;
    const float* kbase = kg + ((size_t)(b * NSEQ)) * D + hh * DH;
    const float* vbase = vg + ((size_t)(b * NSEQ)) * D + hh * DH;
    int len = lengths[b];

    // load Q tile (coalesced float4), init stats
#pragma unroll
    for (int it = 0; it < 4; it++) {
        int idx = it * 256 + tid;
        int r = idx >> 4, dg = (idx & 15) << 2;
        float4 t = *reinterpret_cast<const float4*>(qbase + (size_t)r * D + dg);
        *reinterpret_cast<float4*>(&Qs[r][dg]) = t;
    }
    if (tid < 64) { mrow[tid] = -INFINITY; lrow[tid] = 0.0f; }

    float o[4][4] = {};

    for (int kt = 0; kt < 8; kt++) {
        __syncthreads();   // prior-iteration consumers of U/Vs are done
        // stage K^T and V tiles
#pragma unroll
        for (int it = 0; it < 4; it++) {
            int idx = it * 256 + tid;
            int r = idx >> 4, dg = (idx & 15) << 2;
            float4 t = *reinterpret_cast<const float4*>(kbase + (size_t)(kt * 64 + r) * D + dg);
            U[dg + 0][r] = t.x; U[dg + 1][r] = t.y; U[dg + 2][r] = t.z; U[dg + 3][r] = t.w;
            float4 tv = *reinterpret_cast<const float4*>(vbase + (size_t)(kt * 64 + r) * D + dg);
            *reinterpret_cast<float4*>(&Vs[r][dg]) = tv;
        }
        __syncthreads();

        // S = Q . K^T  (4x4 per thread)
        float s[4][4] = {};
#pragma unroll
        for (int kk = 0; kk < 64; kk++) {
            float a0 = Qs[tr * 4 + 0][kk];
            float a1 = Qs[tr * 4 + 1][kk];
            float a2 = Qs[tr * 4 + 2][kk];
            float a3 = Qs[tr * 4 + 3][kk];
            float4 bb = *reinterpret_cast<const float4*>(&U[kk][tc * 4]);
            s[0][0] += a0 * bb.x; s[0][1] += a0 * bb.y; s[0][2] += a0 * bb.z; s[0][3] += a0 * bb.w;
            s[1][0] += a1 * bb.x; s[1][1] += a1 * bb.y; s[1][2] += a1 * bb.z; s[1][3] += a1 * bb.w;
            s[2][0] += a2 * bb.x; s[2][1] += a2 * bb.y; s[2][2] += a2 * bb.z; s[2][3] += a2 * bb.w;
            s[3][0] += a3 * bb.x; s[3][1] += a3 * bb.y; s[3][2] += a3 * bb.z; s[3][3] += a3 * bb.w;
        }
        __syncthreads();   // all K^T reads done; U can be rewritten

        // scaled + masked scores -> U
#pragma unroll
        for (int i = 0; i < 4; i++)
#pragma unroll
            for (int j = 0; j < 4; j++) {
                int col = kt * 64 + tc * 4 + j;
                U[tr * 4 + i][tc * 4 + j] = (col < len) ? s[i][j] * 0.125f : -1e9f;
            }
        __syncthreads();

        // online softmax stats: tile row max
        float tm = -INFINITY;
#pragma unroll
        for (int e = 0; e < 16; e++) tm = fmaxf(tm, U[row][seg * 16 + e]);
        red[tid] = tm;
        __syncthreads();
        if (seg == 0) {
            float t2 = fmaxf(fmaxf(red[tid], red[tid + 1]), fmaxf(red[tid + 2], red[tid + 3]));
            float nm = fmaxf(mrow[row], t2);
            arow[row] = __expf(mrow[row] - nm);
            mrow[row] = nm;
        }
        __syncthreads();
        // exponentiate in place, partial sums
        float nm = mrow[row];
        float ps = 0.0f;
#pragma unroll
        for (int e = 0; e < 16; e++) {
            float p = __expf(U[row][seg * 16 + e] - nm);
            U[row][seg * 16 + e] = p;
            ps += p;
        }
        red[tid] = ps;
        __syncthreads();
        if (seg == 0)
            lrow[row] = lrow[row] * arow[row] + red[tid] + red[tid + 1] + red[tid + 2] + red[tid + 3];

        // rescale O by alpha, then O += P.V
#pragma unroll
        for (int i = 0; i < 4; i++) {
            float a = arow[tr * 4 + i];
#pragma unroll
            for (int j = 0; j < 4; j++) o[i][j] *= a;
        }
#pragma unroll
        for (int kk = 0; kk < 64; kk++) {
            float a0 = U[tr * 4 + 0][kk];
            float a1 = U[tr * 4 + 1][kk];
            float a2 = U[tr * 4 + 2][kk];
            float a3 = U[tr * 4 + 3][kk];
            float4 bb = *reinterpret_cast<const float4*>(&Vs[kk][tc * 4]);
            o[0][0] += a0 * bb.x; o[0][1] += a0 * bb.y; o[0][2] += a0 * bb.z; o[0][3] += a0 * bb.w;
            o[1][0] += a1 * bb.x; o[1][1] += a1 * bb.y; o[1][2] += a1 * bb.z; o[1][3] += a1 * bb.w;
            o[2][0] += a2 * bb.x; o[2][1] += a2 * bb.y; o[2][2] += a2 * bb.z; o[2][3] += a2 * bb.w;
            o[3][0] += a3 * bb.x; o[3][1] += a3 * bb.y; o[3][2] += a3 * bb.z; o[3][3] += a3 * bb.w;
        }
    }
    __syncthreads();   // final lrow writes visible

    float* obase = ctx + ((size_t)(b * NSEQ + qt * 64)) * D + hh * DH;
#pragma unroll
    for (int i = 0; i < 4; i++) {
        float inv = 1.0f / lrow[tr * 4 + i];
        float4 t = make_float4(o[i][0] * inv, o[i][1] * inv, o[i][2] * inv, o[i][3] * inv);
        *reinterpret_cast<float4*>(obase + (size_t)(tr * 4 + i) * D + tc * 4) = t;
    }
}

// ---------------------------------------------------------------------------
// 5. Final LN output -> attn_res (float32, [N,B,D] layout)
__global__ __launch_bounds__(256) void store_attnres(
    const float* __restrict__ hf, float* __restrict__ out)
{
    int idx = blockIdx.x * 256 + threadIdx.x;  // over N*B*D (output linear)
    int d  = idx & (D - 1);
    int nb = idx >> 9;      // n*B + b
    int b  = nb & (B - 1);
    int n  = nb >> 4;
    out[idx] = hf[((size_t)(b * NSEQ + n)) * D + d];
}

// ---------------------------------------------------------------------------
// 6. la = hf @ inf_W[:D], lb = hf @ inf_W[D:].  One block per token.
__global__ __launch_bounds__(256) void lalb_kernel(
    const float* __restrict__ hf, const float* __restrict__ infW,
    float* __restrict__ la, float* __restrict__ lb)
{
    __shared__ float red[256];
    int t = blockIdx.x, tid = threadIdx.x;
    const float* p = hf + (size_t)t * D;
    float x0 = p[tid], x1 = p[tid + 256];
#pragma unroll
    for (int c = 0; c < C; c++) {
        float pa = x0 * infW[(size_t)tid * C + c] + x1 * infW[(size_t)(tid + 256) * C + c];
        float sa = block_reduce_sum(pa, red);
        if (tid == 0) la[t * C + c] = sa;
        float pb = x0 * infW[(size_t)(tid + 512) * C + c] + x1 * infW[(size_t)(tid + 768) * C + c];
        float sb = block_reduce_sum(pb, red);
        if (tid == 0) lb[t * C + c] = sb;
    }
}

// ---------------------------------------------------------------------------
// 7. logits[b,i,j,:] = la[b,i,:] + lb[b,j,:]; log_softmax over C=3;
//    store float32 at [(i*N+j)*B + b]*C + c.
__global__ __launch_bounds__(256) void logits_kernel(
    const float* __restrict__ la, const float* __restrict__ lb,
    float* __restrict__ out)
{
    int idx = blockIdx.x * 256 + threadIdx.x;  // over N*N*B
    int b  = idx & (B - 1);
    int ij = idx >> 4;
    int j  = ij & (NSEQ - 1);
    int i  = ij >> 9;
    const float* pa = la + ((size_t)(b * NSEQ + i)) * C;
    const float* pb = lb + ((size_t)(b * NSEQ + j)) * C;
    float l0 = pa[0] + pb[0];
    float l1 = pa[1] + pb[1];
    float l2 = pa[2] + pb[2];
    float m = fmaxf(l0, fmaxf(l1, l2));
    float lse = m + logf(__expf(l0 - m) + __expf(l1 - m) + __expf(l2 - m));
    out[(size_t)idx * 3 + 0] = l0 - lse;
    out[(size_t)idx * 3 + 1] = l1 - lse;
    out[(size_t)idx * 3 + 2] = l2 - lse;
}

// ---------------------------------------------------------------------------
extern "C" void kernel_launch(void* const* d_in, const int* in_sizes, int n_in,
                              void* d_out, int out_size, void* d_ws, size_t ws_size,
                              hipStream_t stream)
{
    const int*   src     = (const int*)  d_in[0];
    const int*   lengths = (const int*)  d_in[1];
    const float* emb     = (const float*)d_in[2];
    const float* ln1_g   = (const float*)d_in[3];
    const float* ln1_b   = (const float*)d_in[4];
    const float* Wq      = (const float*)d_in[5];
    const float* bq      = (const float*)d_in[6];
    const float* Wk      = (const float*)d_in[7];
    const float* bk      = (const float*)d_in[8];
    const float* Wv      = (const float*)d_in[9];
    const float* bv      = (const float*)d_in[10];
    const float* Wo      = (const float*)d_in[11];
    const float* bo      = (const float*)d_in[12];
    const float* ln2_g   = (const float*)d_in[13];
    const float* ln2_b   = (const float*)d_in[14];
    const float* W1      = (const float*)d_in[15];
    const float* b1      = (const float*)d_in[16];
    const float* W2      = (const float*)d_in[17];
    const float* b2      = (const float*)d_in[18];
    const float* lnf_g   = (const float*)d_in[19];
    const float* lnf_b   = (const float*)d_in[20];
    const float* infW    = (const float*)d_in[21];

    // Workspace layout (fp32), 5*BND floats = exactly 80 MiB
    float* ws  = (float*)d_ws;
    float* x   = ws;
    float* h   = x + BND;
    float* big = h + BND;
    float* qb  = big;
    float* kb  = big + BND;
    float* vb  = big + 2 * BND;
    float* la  = big;                       // big is free after the L layers
    float* lb  = la + (size_t)M * C;

    dim3 blk(256);
    dim3 g_dd(D / 64, M / 64);        // 8 x 128
    dim3 g_dffh(DFF / 64, M / 128);   // 32 x 64 (half the tokens)
    dim3 g_ddh(D / 64, M / 128);      // 8 x 64
    dim3 g_attn(NSEQ / 64, H, B);     // 8 x 8 x 16 = 1024 blocks

    embed_pe_kernel<<<BND / 256, blk, 0, stream>>>(src, emb, x);

    for (int l = 0; l < L; l++) {
        size_t wdd = (size_t)l * D * D, bd = (size_t)l * D;
        size_t wdf = (size_t)l * D * DFF, bf = (size_t)l * DFF;
        ln_kernel<<<M, blk, 0, stream>>>(x, ln1_g + bd, ln1_b + bd, h);
        gemm_kernel<false, false><<<g_dd, blk, 0, stream>>>(h, Wq + wdd, bq + bd, qb, D, D);
        gemm_kernel<false, false><<<g_dd, blk, 0, stream>>>(h, Wk + wdd, bk + bd, kb, D, D);
        gemm_kernel<false, false><<<g_dd, blk, 0, stream>>>(h, Wv + wdd, bv + bd, vb, D, D);
        attn_tile_kernel<<<g_attn, blk, 0, stream>>>(qb, kb, vb, lengths, h);
        gemm_kernel<true, false><<<g_dd, blk, 0, stream>>>(h, Wo + wdd, bo + bd, x, D, D);
        ln_kernel<<<M, blk, 0, stream>>>(x, ln2_g + bd, ln2_b + bd, h);
        // FFN in two half-M passes so the hidden fits in big
        for (int hf = 0; hf < 2; hf++) {
            const float* hp = h + (size_t)hf * (M / 2) * D;
            float*       xp = x + (size_t)hf * (M / 2) * D;
            gemm_kernel<false, true><<<g_dffh, blk, 0, stream>>>(hp, W1 + wdf, b1 + bf, big, D, DFF);
            gemm_kernel<true, false><<<g_ddh, blk, 0, stream>>>(big, W2 + wdf, b2 + bd, xp, DFF, D);
        }
    }

    ln_kernel<<<M, blk, 0, stream>>>(x, lnf_g, lnf_b, h);
    store_attnres<<<(NSEQ * B * D) / 256, blk, 0, stream>>>(h, (float*)d_out);
    lalb_kernel<<<M, blk, 0, stream>>>(h, infW, la, lb);
    logits_kernel<<<(NSEQ * NSEQ * B) / 256, blk, 0, stream>>>(la, lb, (float*)d_out + (size_t)NSEQ * B * D);
}